// Round 9
// baseline (1119.192 us; speedup 1.0000x reference)
//
#include <hip/hip_runtime.h>
#include <hip/hip_bf16.h>

#define GLOBAL_AS __attribute__((address_space(1)))
#define LDS_AS    __attribute__((address_space(3)))

typedef __bf16 bf16x8 __attribute__((ext_vector_type(8)));
typedef __bf16 bf16x4 __attribute__((ext_vector_type(4)));
typedef float  f32x4v __attribute__((ext_vector_type(4)));

// ---------------- K1: RMSNorm -> t_f32, t_bf16 ----------------
__global__ __launch_bounds__(256) void k_rmsnorm(const float* __restrict__ x,
        const float* __restrict__ sc, float* __restrict__ t32,
        __bf16* __restrict__ t16)
{
    const int t = blockIdx.x, tid = threadIdx.x;
    const float4 v = ((const float4*)(x + (size_t)t * 1024))[tid];
    float ss = v.x*v.x + v.y*v.y + v.z*v.z + v.w*v.w;
    #pragma unroll
    for (int s = 32; s; s >>= 1) ss += __shfl_xor(ss, s, 64);
    __shared__ float red[4];
    if ((tid & 63) == 0) red[tid >> 6] = ss;
    __syncthreads();
    const float tot = red[0] + red[1] + red[2] + red[3];
    const float rs = rsqrtf(tot * (1.0f / 1024.0f) + 1e-5f);
    const float4 s4 = ((const float4*)sc)[tid];
    float4 o;
    o.x = v.x * rs * s4.x; o.y = v.y * rs * s4.y;
    o.z = v.z * rs * s4.z; o.w = v.w * rs * s4.w;
    ((float4*)(t32 + (size_t)t * 1024))[tid] = o;
    bf16x4 p;
    p[0] = (__bf16)o.x; p[1] = (__bf16)o.y; p[2] = (__bf16)o.z; p[3] = (__bf16)o.w;
    ((bf16x4*)(t16 + (size_t)t * 1024))[tid] = p;
}

// ---------------- K2: gate logits (fp32) + top4 + softmax ----------------
__global__ __launch_bounds__(256) void k_gate(const float* __restrict__ t32,
        const float* __restrict__ gw, const float* __restrict__ gb,
        int* __restrict__ idx, float* __restrict__ ew)
{
    const int t = blockIdx.x, tid = threadIdx.x;
    __shared__ float4 tl[256];
    __shared__ float part[4][64];
    tl[tid] = ((const float4*)(t32 + (size_t)t * 1024))[tid];
    __syncthreads();
    const int q = tid >> 6, e = tid & 63;
    const float4* w4 = (const float4*)(gw + (size_t)e * 1024 + q * 256);
    const float4* a4 = &tl[q * 64];
    float acc = 0.0f;
    #pragma unroll 8
    for (int i = 0; i < 64; ++i) {
        const float4 a = a4[i], b = w4[i];
        acc += a.x*b.x + a.y*b.y + a.z*b.z + a.w*b.w;
    }
    part[q][e] = acc;
    __syncthreads();
    if (tid < 64) {
        float cur = part[0][tid] + part[1][tid] + part[2][tid] + part[3][tid] + gb[tid];
        float vals[4]; int ids[4];
        #pragma unroll
        for (int k = 0; k < 4; ++k) {
            float m = cur;
            #pragma unroll
            for (int s = 32; s; s >>= 1) m = fmaxf(m, __shfl_xor(m, s, 64));
            const unsigned long long b = __ballot(cur == m);
            const int bi = __ffsll(b) - 1;
            vals[k] = m; ids[k] = bi;
            if (tid == bi) cur = -3.0e38f;
        }
        float ex[4], s = 0.0f;
        #pragma unroll
        for (int k = 0; k < 4; ++k) { ex[k] = expf(vals[k] - vals[0]); s += ex[k]; }
        if (tid < 4) { idx[t * 4 + tid] = ids[tid]; ew[t * 4 + tid] = ex[tid] / s; }
    }
}

// ---------------- K3: bucket (token,expert) pairs by expert ----------------
__global__ __launch_bounds__(256) void k_bucket(const int* __restrict__ idx,
        const float* __restrict__ ewv, int* __restrict__ eoff,
        int* __restrict__ slot_token, float* __restrict__ slot_ew,
        int* __restrict__ token_slots)
{
    __shared__ int cnt[64], cur[64];
    const int tid = threadIdx.x;
    if (tid < 64) cnt[tid] = 0;
    __syncthreads();
    for (int p = tid; p < 4096; p += 256) atomicAdd(&cnt[idx[p]], 1);
    __syncthreads();
    if (tid == 0) {
        int s = 0;
        for (int e = 0; e < 64; ++e) { eoff[e] = s; cur[e] = s; s += cnt[e]; }
        eoff[64] = s;
    }
    __syncthreads();
    for (int p = tid; p < 4096; p += 256) {
        const int e = idx[p];
        const int s = atomicAdd(&cur[e], 1);
        slot_token[s] = p >> 2;
        slot_ew[s] = ewv[p];
        token_slots[p] = s;
    }
}

// ---------------- PROBE 1: pure linear read of W1 (fill-pattern, reads) ----------------
__global__ __launch_bounds__(256) void k_probe_lin(const float* __restrict__ W,
        int reps)
{
    const size_t tid = (size_t)blockIdx.x * 256 + threadIdx.x;
    float4 acc = {0.f, 0.f, 0.f, 0.f};
    const float4* p = (const float4*)W;
    for (int r = 0; r < reps; ++r) {
        #pragma unroll 8
        for (size_t i = tid; i < 33554432ull; i += 524288ull) {   // 512 MiB sweep
            const float4 v = p[i];
            acc.x += v.x; acc.y += v.y; acc.z += v.z; acc.w += v.w;
        }
    }
    asm volatile("" :: "v"(acc.x), "v"(acc.y), "v"(acc.z), "v"(acc.w));
}

// ---------------- PROBE 2: byte-exact GEMM1 W access pattern, no compute ----------------
// 1024 blocks = (e,nt) panels; per kt: 128 rows x 256 B at 4 KB stride.
__global__ __launch_bounds__(256) void k_probe_gpat(const float* __restrict__ W,
        int reps)
{
    const int d = blockIdx.x;
    const int e = (d & 7) * 8 + ((d >> 3) & 7);
    const int nt = d >> 6;
    const int tid = threadIdx.x;
    const float* Wb = W + (size_t)e * 2048 * 1024 + (size_t)nt * 128 * 1024;
    float4 acc = {0.f, 0.f, 0.f, 0.f};
    for (int r = 0; r < reps; ++r) {
        #pragma unroll 1
        for (int kt = 0; kt < 16; ++kt) {
            #pragma unroll
            for (int it = 0; it < 8; ++it) {
                const int fid = it * 256 + tid;
                const float4 v = *(const float4*)(Wb + (size_t)(fid >> 4) * 1024
                                                  + kt * 64 + (fid & 15) * 4);
                acc.x += v.x; acc.y += v.y; acc.z += v.z; acc.w += v.w;
            }
        }
    }
    asm volatile("" :: "v"(acc.x), "v"(acc.y), "v"(acc.z), "v"(acc.w));
}

// ---------------- K4/K5: grouped GEMM (round-3 structure, best known) ----------------
template<int MODE>
__global__ __launch_bounds__(256, 2) void k_gemm(
        const float* __restrict__ W, const float* __restrict__ Bias,
        const __bf16* __restrict__ A,
        const int* __restrict__ eoff, const int* __restrict__ slot_token,
        const float* __restrict__ slot_ew,
        __bf16* __restrict__ act_out, __bf16* __restrict__ o_buf)
{
    constexpr int NPE = (MODE == 0) ? 2048 : 1024;
    const int d  = blockIdx.y * gridDim.x + blockIdx.x;
    const int e  = (d & 7) * 8 + ((d >> 3) & 7);
    const int nt = d >> 6;
    const int ph = (d * 7) & 15;
    const int off = eoff[e];
    const int count = eoff[e + 1] - off;
    if (count == 0) return;
    const int tid = threadIdx.x;
    const int wv = tid >> 6, l = tid & 63;
    const int wm = wv >> 1, wn = wv & 1;

    __shared__ __attribute__((aligned(16))) unsigned char lds[2][32768];

    const float* Wb = W + (size_t)e * NPE * 1024 + (size_t)nt * 128 * 1024;

#define KCOL(kt) ((ph + (kt)) & 15)

#define DMA_A(sbuf, kt) do {                                                   \
    const int kc_ = KCOL(kt);                                                  \
    _Pragma("unroll")                                                          \
    for (int i_ = 0; i_ < 4; ++i_)                                             \
        __builtin_amdgcn_global_load_lds(                                      \
            (const GLOBAL_AS void*)(asrc[i_] + kc_ * 128),                     \
            (LDS_AS void*)&lds[sbuf][(wv * 4 + i_) * 1024], 16, 0, 0);         \
    } while (0)

#define LOAD_B(dst, kt) do {                                                   \
    const int kc_ = KCOL(kt);                                                  \
    _Pragma("unroll")                                                          \
    for (int it_ = 0; it_ < 8; ++it_) {                                        \
        const int fid_ = it_ * 256 + tid;                                      \
        dst[it_] = *(const float4*)(Wb + (size_t)(fid_ >> 4) * 1024            \
                                    + kc_ * 64 + (fid_ & 15) * 4);             \
    } } while (0)

#define WRITE_B(src, sbuf) do {                                                \
    _Pragma("unroll")                                                          \
    for (int it_ = 0; it_ < 8; ++it_) {                                        \
        const int fid_ = it_ * 256 + tid;                                      \
        const int row_ = fid_ >> 4, c4_ = fid_ & 15;                           \
        bf16x4 p_;                                                             \
        p_[0] = (__bf16)src[it_].x; p_[1] = (__bf16)src[it_].y;                \
        p_[2] = (__bf16)src[it_].z; p_[3] = (__bf16)src[it_].w;                \
        *(bf16x4*)(&lds[sbuf][16384 + row_ * 128 +                             \
                   ((c4_ * 8) ^ ((row_ & 7) << 4))]) = p_;                     \
    } } while (0)

#define COMPUTE(cbuf) do {                                                     \
    _Pragma("unroll")                                                          \
    for (int kk_ = 0; kk_ < 2; ++kk_) {                                        \
        bf16x8 af_[4], bf_[4];                                                 \
        _Pragma("unroll")                                                      \
        for (int m_ = 0; m_ < 4; ++m_) {                                       \
            const int row_ = wm * 64 + m_ * 16 + (l & 15);                     \
            af_[m_] = *(const bf16x8*)(&lds[cbuf][row_ * 128 +                 \
                      ((kk_ * 64 + ((l >> 4) * 16)) ^ ((row_ & 7) << 4))]);    \
        }                                                                      \
        _Pragma("unroll")                                                      \
        for (int n_ = 0; n_ < 4; ++n_) {                                       \
            const int row_ = wn * 64 + n_ * 16 + (l & 15);                     \
            bf_[n_] = *(const bf16x8*)(&lds[cbuf][16384 + row_ * 128 +         \
                      ((kk_ * 64 + ((l >> 4) * 16)) ^ ((row_ & 7) << 4))]);    \
        }                                                                      \
        _Pragma("unroll")                                                      \
        for (int m_ = 0; m_ < 4; ++m_)                                         \
            _Pragma("unroll")                                                  \
            for (int n_ = 0; n_ < 4; ++n_)                                     \
                acc[m_][n_] = __builtin_amdgcn_mfma_f32_16x16x32_bf16(         \
                                  af_[m_], bf_[n_], acc[m_][n_], 0, 0, 0);     \
    } } while (0)

    for (int mt = 0; mt * 128 < count; ++mt) {
        const unsigned char* asrc[4];
        #pragma unroll
        for (int i = 0; i < 4; ++i) {
            const int chunk = wv * 4 + i;
            const int row = chunk * 8 + (l >> 3);
            const int colbyte = ((l & 7) ^ (l >> 3)) << 4;
            int arow;
            if (MODE == 0) {
                int slot = off + mt * 128 + row;
                const int smax = off + count - 1;
                if (slot > smax) slot = smax;
                arow = slot_token[slot];
            } else {
                arow = off + mt * 128 + row;
            }
            asrc[i] = (const unsigned char*)A + (size_t)arow * 2048 + colbyte;
        }

        f32x4v acc[4][4];
        #pragma unroll
        for (int m = 0; m < 4; ++m)
            #pragma unroll
            for (int n = 0; n < 4; ++n)
                acc[m][n] = f32x4v{0.f, 0.f, 0.f, 0.f};

        float4 bvA[8], bvB[8];

        // ---- prologue ----
        DMA_A(0, 0);
        __builtin_amdgcn_sched_barrier(0);
        LOAD_B(bvA, 0);
        WRITE_B(bvA, 0);
        __builtin_amdgcn_sched_barrier(0);
        LOAD_B(bvA, 1);
        asm volatile("s_waitcnt lgkmcnt(0)" ::: "memory");
        __builtin_amdgcn_sched_barrier(0);
        __builtin_amdgcn_s_barrier();

        #pragma unroll 1
        for (int p = 0; p < 7; ++p) {
            const int kt0 = 2 * p, kt1 = 2 * p + 1;
            DMA_A(1, kt0 + 1);
            __builtin_amdgcn_sched_barrier(0);
            LOAD_B(bvB, kt0 + 2);
            __builtin_amdgcn_sched_barrier(0);
            COMPUTE(0);
            WRITE_B(bvA, 1);
            asm volatile("s_waitcnt vmcnt(8) lgkmcnt(0)" ::: "memory");
            __builtin_amdgcn_sched_barrier(0);
            __builtin_amdgcn_s_barrier();
            DMA_A(0, kt1 + 1);
            __builtin_amdgcn_sched_barrier(0);
            LOAD_B(bvA, kt1 + 2);
            __builtin_amdgcn_sched_barrier(0);
            COMPUTE(1);
            WRITE_B(bvB, 0);
            asm volatile("s_waitcnt vmcnt(8) lgkmcnt(0)" ::: "memory");
            __builtin_amdgcn_sched_barrier(0);
            __builtin_amdgcn_s_barrier();
        }

        // ---- tail: kt=14,15 ----
        DMA_A(1, 15);
        __builtin_amdgcn_sched_barrier(0);
        COMPUTE(0);
        WRITE_B(bvA, 1);
        asm volatile("s_waitcnt vmcnt(0) lgkmcnt(0)" ::: "memory");
        __builtin_amdgcn_sched_barrier(0);
        __builtin_amdgcn_s_barrier();
        COMPUTE(1);

        // ---- epilogue ----
        #pragma unroll
        for (int m = 0; m < 4; ++m) {
            #pragma unroll
            for (int n = 0; n < 4; ++n) {
                #pragma unroll
                for (int j = 0; j < 4; ++j) {
                    const int row  = wm * 64 + m * 16 + (l >> 4) * 4 + j;
                    const int coll = wn * 64 + n * 16 + (l & 15);
                    const int gn = nt * 128 + coll;
                    const int gm = mt * 128 + row;
                    if (MODE == 0) {
                        float v = acc[m][n][j] + Bias[(size_t)e * NPE + gn];
                        const float partner = __shfl_xor(v, 1, 64);
                        if (!(l & 1) && gm < count) {
                            const float g  = fminf(v, 7.0f);
                            const float lv = fminf(fmaxf(partner, -7.0f), 7.0f);
                            const float r  = g / (1.0f + expf(-1.702f * g)) * (lv + 1.0f);
                            act_out[(size_t)(off + gm) * 1024 + (gn >> 1)] = (__bf16)r;
                        }
                    } else {
                        if (gm < count) {
                            const int slot = off + gm;
                            const float v = acc[m][n][j] + Bias[(size_t)e * NPE + gn];
                            o_buf[(size_t)slot * 1024 + gn] = (__bf16)(v * slot_ew[slot]);
                        }
                    }
                }
            }
        }
        __builtin_amdgcn_s_barrier();   // protect LDS reuse across mt
    }
#undef DMA_A
#undef LOAD_B
#undef WRITE_B
#undef COMPUTE
#undef KCOL
}

// ---------------- K6: out = x + sum_k o_buf[slot(t,k)] (obuf bf16) ----------------
__global__ __launch_bounds__(256) void k_combine(const float* __restrict__ x,
        const __bf16* __restrict__ o_buf, const int* __restrict__ tslot,
        float* __restrict__ out)
{
    const int t = blockIdx.x, tid = threadIdx.x;
    float4 r = ((const float4*)(x + (size_t)t * 1024))[tid];
    #pragma unroll
    for (int k = 0; k < 4; ++k) {
        const int s = tslot[t * 4 + k];
        const bf16x4 o = ((const bf16x4*)(o_buf + (size_t)s * 1024))[tid];
        r.x += (float)o[0]; r.y += (float)o[1];
        r.z += (float)o[2]; r.w += (float)o[3];
    }
    ((float4*)(out + (size_t)t * 1024))[tid] = r;
}

extern "C" void kernel_launch(void* const* d_in, const int* in_sizes, int n_in,
                              void* d_out, int out_size, void* d_ws, size_t ws_size,
                              hipStream_t stream)
{
    const float* x   = (const float*)d_in[0];
    const float* nsc = (const float*)d_in[1];
    const float* gw  = (const float*)d_in[2];
    const float* gb  = (const float*)d_in[3];
    const float* w1  = (const float*)d_in[4];
    const float* b1  = (const float*)d_in[5];
    const float* w2  = (const float*)d_in[6];
    const float* b2  = (const float*)d_in[7];
    float* out = (float*)d_out;
    (void)in_sizes; (void)n_in; (void)out_size; (void)ws_size;

    char* ws = (char*)d_ws;
    float*  t32   = (float*)(ws);                                  // 4 MiB
    __bf16* t16   = (__bf16*)(ws + (4u  << 20));                   // 2 MiB
    __bf16* act   = (__bf16*)(ws + (6u  << 20));                   // 8.4 MiB
    __bf16* obuf  = (__bf16*)(ws + (16u << 20));                   // 8.4 MiB
    int*    idx   = (int*)  (ws + (34u << 20));
    float*  ew    = (float*)(ws + (34u << 20) + 1 * 65536);
    int*    stok  = (int*)  (ws + (34u << 20) + 2 * 65536);
    float*  sew   = (float*)(ws + (34u << 20) + 3 * 65536);
    int*    tslot = (int*)  (ws + (34u << 20) + 4 * 65536);
    int*    eoff  = (int*)  (ws + (34u << 20) + 5 * 65536);

    // INSTRUMENTATION (this round only): read-BW probes over W1, reps=5 each
    // so they surface above the ~330us harness poison fills in rocprof top-5.
    // probe_lin = pure sequential read ceiling; probe_gpat = GEMM's exact
    // 256B-strip@4KB-stride pattern ceiling. No output writes (asm sink).
    k_probe_lin <<<2048, 256, 0, stream>>>(w1, 5);
    k_probe_gpat<<<1024, 256, 0, stream>>>(w1, 5);

    k_rmsnorm<<<1024, 256, 0, stream>>>(x, nsc, t32, t16);
    k_gate   <<<1024, 256, 0, stream>>>(t32, gw, gb, idx, ew);
    k_bucket <<<   1, 256, 0, stream>>>(idx, ew, eoff, stok, sew, tslot);
    k_gemm<0><<<dim3(16, 64), 256, 0, stream>>>(w1, b1, t16, eoff, stok, sew, act, nullptr);
    k_gemm<1><<<dim3( 8, 64), 256, 0, stream>>>(w2, b2, act, eoff, stok, sew, nullptr, obuf);
    k_combine<<<1024, 256, 0, stream>>>(x, obuf, tslot, out);
}

// Round 10
// 909.326 us; speedup vs baseline: 1.2308x; 1.2308x over previous
//
#include <hip/hip_runtime.h>
#include <hip/hip_bf16.h>

typedef __bf16 bf16x8 __attribute__((ext_vector_type(8)));
typedef __bf16 bf16x4 __attribute__((ext_vector_type(4)));
typedef float  f32x4v __attribute__((ext_vector_type(4)));

// ---------------- K1: RMSNorm -> t_f32, t_bf16 ----------------
__global__ __launch_bounds__(256) void k_rmsnorm(const float* __restrict__ x,
        const float* __restrict__ sc, float* __restrict__ t32,
        __bf16* __restrict__ t16)
{
    const int t = blockIdx.x, tid = threadIdx.x;
    const float4 v = ((const float4*)(x + (size_t)t * 1024))[tid];
    float ss = v.x*v.x + v.y*v.y + v.z*v.z + v.w*v.w;
    #pragma unroll
    for (int s = 32; s; s >>= 1) ss += __shfl_xor(ss, s, 64);
    __shared__ float red[4];
    if ((tid & 63) == 0) red[tid >> 6] = ss;
    __syncthreads();
    const float tot = red[0] + red[1] + red[2] + red[3];
    const float rs = rsqrtf(tot * (1.0f / 1024.0f) + 1e-5f);
    const float4 s4 = ((const float4*)sc)[tid];
    float4 o;
    o.x = v.x * rs * s4.x; o.y = v.y * rs * s4.y;
    o.z = v.z * rs * s4.z; o.w = v.w * rs * s4.w;
    ((float4*)(t32 + (size_t)t * 1024))[tid] = o;
    bf16x4 p;
    p[0] = (__bf16)o.x; p[1] = (__bf16)o.y; p[2] = (__bf16)o.z; p[3] = (__bf16)o.w;
    ((bf16x4*)(t16 + (size_t)t * 1024))[tid] = p;
}

// ---------------- K2: gate logits (fp32) + top4 + softmax ----------------
__global__ __launch_bounds__(256) void k_gate(const float* __restrict__ t32,
        const float* __restrict__ gw, const float* __restrict__ gb,
        int* __restrict__ idx, float* __restrict__ ew)
{
    const int t = blockIdx.x, tid = threadIdx.x;
    __shared__ float4 tl[256];
    __shared__ float part[4][64];
    tl[tid] = ((const float4*)(t32 + (size_t)t * 1024))[tid];
    __syncthreads();
    const int q = tid >> 6, e = tid & 63;
    const float4* w4 = (const float4*)(gw + (size_t)e * 1024 + q * 256);
    const float4* a4 = &tl[q * 64];
    float acc = 0.0f;
    #pragma unroll 8
    for (int i = 0; i < 64; ++i) {
        const float4 a = a4[i], b = w4[i];
        acc += a.x*b.x + a.y*b.y + a.z*b.z + a.w*b.w;
    }
    part[q][e] = acc;
    __syncthreads();
    if (tid < 64) {
        float cur = part[0][tid] + part[1][tid] + part[2][tid] + part[3][tid] + gb[tid];
        float vals[4]; int ids[4];
        #pragma unroll
        for (int k = 0; k < 4; ++k) {
            float m = cur;
            #pragma unroll
            for (int s = 32; s; s >>= 1) m = fmaxf(m, __shfl_xor(m, s, 64));
            const unsigned long long b = __ballot(cur == m);
            const int bi = __ffsll(b) - 1;
            vals[k] = m; ids[k] = bi;
            if (tid == bi) cur = -3.0e38f;
        }
        float ex[4], s = 0.0f;
        #pragma unroll
        for (int k = 0; k < 4; ++k) { ex[k] = expf(vals[k] - vals[0]); s += ex[k]; }
        if (tid < 4) { idx[t * 4 + tid] = ids[tid]; ew[t * 4 + tid] = ex[tid] / s; }
    }
}

// ---------------- K3: bucket (token,expert) pairs by expert ----------------
__global__ __launch_bounds__(256) void k_bucket(const int* __restrict__ idx,
        const float* __restrict__ ewv, int* __restrict__ eoff,
        int* __restrict__ slot_token, float* __restrict__ slot_ew,
        int* __restrict__ token_slots)
{
    __shared__ int cnt[64], cur[64];
    const int tid = threadIdx.x;
    if (tid < 64) cnt[tid] = 0;
    __syncthreads();
    for (int p = tid; p < 4096; p += 256) atomicAdd(&cnt[idx[p]], 1);
    __syncthreads();
    if (tid == 0) {
        int s = 0;
        for (int e = 0; e < 64; ++e) { eoff[e] = s; cur[e] = s; s += cnt[e]; }
        eoff[64] = s;
    }
    __syncthreads();
    for (int p = tid; p < 4096; p += 256) {
        const int e = idx[p];
        const int s = atomicAdd(&cur[e], 1);
        slot_token[s] = p >> 2;
        slot_ew[s] = ewv[p];
        token_slots[p] = s;
    }
}

// ---------------- K4/K5: barrier-free reg-direct grouped GEMM ----------------
// Probe-style: NO LDS, NO barriers. Per-wave 32Mx64N tile; A (bf16) and W
// (fp32, cvt on arrival) stream global->regs from stable per-lane bases with
// compile-time immediate offsets; 2-deep double-buffered prefetch; waves
// free-run like k_probe_lin (which hit the 2.85 TB/s fetch cap).
template<int MODE>
__global__ __launch_bounds__(256, 3) void k_gemm(
        const float* __restrict__ W, const float* __restrict__ Bias,
        const __bf16* __restrict__ A,
        const int* __restrict__ eoff, const int* __restrict__ slot_token,
        const float* __restrict__ slot_ew,
        __bf16* __restrict__ act_out, __bf16* __restrict__ o_buf)
{
    constexpr int NPE = (MODE == 0) ? 2048 : 1024;
    const int e  = blockIdx.y;
    const int nt = blockIdx.x;                     // 64-col W panel
    const int off = eoff[e];
    const int count = eoff[e + 1] - off;
    if (count == 0) return;
    const int tid = threadIdx.x;
    const int wv = tid >> 6, l = tid & 63;
    const int lrow = l & 15, lq = l >> 4;

    // W bases: fragment n reads W row (nt*64 + n*16 + lrow), k-quad lq
    const char* bbase[4];
    #pragma unroll
    for (int n = 0; n < 4; ++n)
        bbase[n] = (const char*)(W + ((size_t)e * NPE + nt * 64 + n * 16 + lrow) * 1024)
                   + lq * 32;

#define LOADB(dst, kk) do {                                                    \
    _Pragma("unroll")                                                          \
    for (int n_ = 0; n_ < 4; ++n_) {                                           \
        dst[2*n_]   = *(const float4*)(bbase[n_] + (kk) * 128);                \
        dst[2*n_+1] = *(const float4*)(bbase[n_] + (kk) * 128 + 16);           \
    } } while (0)

#define LOADA(dst, kk) do {                                                    \
    _Pragma("unroll")                                                          \
    for (int m_ = 0; m_ < 2; ++m_)                                             \
        dst[m_] = *(const bf16x8*)(abase[m_] + (kk) * 64);                     \
    } while (0)

#define CVT(bf, raw) do {                                                      \
    _Pragma("unroll")                                                          \
    for (int n_ = 0; n_ < 4; ++n_) {                                           \
        bf[n_][0] = (__bf16)raw[2*n_].x;   bf[n_][1] = (__bf16)raw[2*n_].y;    \
        bf[n_][2] = (__bf16)raw[2*n_].z;   bf[n_][3] = (__bf16)raw[2*n_].w;    \
        bf[n_][4] = (__bf16)raw[2*n_+1].x; bf[n_][5] = (__bf16)raw[2*n_+1].y;  \
        bf[n_][6] = (__bf16)raw[2*n_+1].z; bf[n_][7] = (__bf16)raw[2*n_+1].w;  \
    } } while (0)

#define MFMA8(av, bf) do {                                                     \
    _Pragma("unroll")                                                          \
    for (int m_ = 0; m_ < 2; ++m_)                                             \
        _Pragma("unroll")                                                      \
        for (int n_ = 0; n_ < 4; ++n_)                                         \
            acc[m_][n_] = __builtin_amdgcn_mfma_f32_16x16x32_bf16(             \
                              av[m_], bf[n_], acc[m_][n_], 0, 0, 0);           \
    } while (0)

    for (int mt = 0; mt * 128 < count; ++mt) {
        // A bases: fragment m reads A row for slot (off + mt*128 + wv*32 + m*16 + lrow)
        const char* abase[2];
        #pragma unroll
        for (int m = 0; m < 2; ++m) {
            int slot = off + mt * 128 + wv * 32 + m * 16 + lrow;
            const int smax = off + count - 1;
            if (slot > smax) slot = smax;          // clamp pad rows (discarded)
            const int arow = (MODE == 0) ? slot_token[slot] : slot;
            abase[m] = (const char*)(A + (size_t)arow * 1024) + lq * 16;
        }

        f32x4v acc[2][4];
        #pragma unroll
        for (int m = 0; m < 2; ++m)
            #pragma unroll
            for (int n = 0; n < 4; ++n)
                acc[m][n] = f32x4v{0.f, 0.f, 0.f, 0.f};

        float4 brA[8], brB[8];
        bf16x8 aA[2], aB[2];

        // prologue: 2 K-steps in flight
        LOADB(brA, 0); LOADA(aA, 0);
        LOADB(brB, 1); LOADA(aB, 1);

        #pragma unroll
        for (int kk = 0; kk < 32; kk += 2) {
            {   // step kk (set A)
                bf16x8 bf[4];
                CVT(bf, brA);                       // waits set-A loads only
                if (kk + 2 < 32) LOADB(brA, kk + 2);
                MFMA8(aA, bf);
                if (kk + 2 < 32) LOADA(aA, kk + 2);
            }
            {   // step kk+1 (set B)
                bf16x8 bf[4];
                CVT(bf, brB);
                if (kk + 3 < 32) LOADB(brB, kk + 3);
                MFMA8(aB, bf);
                if (kk + 3 < 32) LOADA(aB, kk + 3);
            }
        }

        // ---- epilogue ----
        #pragma unroll
        for (int m = 0; m < 2; ++m) {
            #pragma unroll
            for (int n = 0; n < 4; ++n) {
                #pragma unroll
                for (int j = 0; j < 4; ++j) {
                    const int row = wv * 32 + m * 16 + lq * 4 + j;
                    const int gn = nt * 64 + n * 16 + lrow;
                    const int gm = mt * 128 + row;
                    if (MODE == 0) {
                        float v = acc[m][n][j] + Bias[(size_t)e * NPE + gn];
                        const float partner = __shfl_xor(v, 1, 64);
                        if (!(l & 1) && gm < count) {
                            const float g  = fminf(v, 7.0f);
                            const float lv = fminf(fmaxf(partner, -7.0f), 7.0f);
                            const float r  = g / (1.0f + expf(-1.702f * g)) * (lv + 1.0f);
                            act_out[(size_t)(off + gm) * 1024 + (gn >> 1)] = (__bf16)r;
                        }
                    } else {
                        if (gm < count) {
                            const int slot = off + gm;
                            const float v = acc[m][n][j] + Bias[(size_t)e * NPE + gn];
                            o_buf[(size_t)slot * 1024 + gn] = (__bf16)(v * slot_ew[slot]);
                        }
                    }
                }
            }
        }
    }
#undef LOADB
#undef LOADA
#undef CVT
#undef MFMA8
}

// ---------------- K6: out = x + sum_k o_buf[slot(t,k)] (obuf bf16) ----------------
__global__ __launch_bounds__(256) void k_combine(const float* __restrict__ x,
        const __bf16* __restrict__ o_buf, const int* __restrict__ tslot,
        float* __restrict__ out)
{
    const int t = blockIdx.x, tid = threadIdx.x;
    float4 r = ((const float4*)(x + (size_t)t * 1024))[tid];
    #pragma unroll
    for (int k = 0; k < 4; ++k) {
        const int s = tslot[t * 4 + k];
        const bf16x4 o = ((const bf16x4*)(o_buf + (size_t)s * 1024))[tid];
        r.x += (float)o[0]; r.y += (float)o[1];
        r.z += (float)o[2]; r.w += (float)o[3];
    }
    ((float4*)(out + (size_t)t * 1024))[tid] = r;
}

extern "C" void kernel_launch(void* const* d_in, const int* in_sizes, int n_in,
                              void* d_out, int out_size, void* d_ws, size_t ws_size,
                              hipStream_t stream)
{
    const float* x   = (const float*)d_in[0];
    const float* nsc = (const float*)d_in[1];
    const float* gw  = (const float*)d_in[2];
    const float* gb  = (const float*)d_in[3];
    const float* w1  = (const float*)d_in[4];
    const float* b1  = (const float*)d_in[5];
    const float* w2  = (const float*)d_in[6];
    const float* b2  = (const float*)d_in[7];
    float* out = (float*)d_out;
    (void)in_sizes; (void)n_in; (void)out_size; (void)ws_size;

    char* ws = (char*)d_ws;
    float*  t32   = (float*)(ws);                                  // 4 MiB
    __bf16* t16   = (__bf16*)(ws + (4u  << 20));                   // 2 MiB
    __bf16* act   = (__bf16*)(ws + (6u  << 20));                   // 8.4 MiB
    __bf16* obuf  = (__bf16*)(ws + (16u << 20));                   // 8.4 MiB
    int*    idx   = (int*)  (ws + (34u << 20));
    float*  ew    = (float*)(ws + (34u << 20) + 1 * 65536);
    int*    stok  = (int*)  (ws + (34u << 20) + 2 * 65536);
    float*  sew   = (float*)(ws + (34u << 20) + 3 * 65536);
    int*    tslot = (int*)  (ws + (34u << 20) + 4 * 65536);
    int*    eoff  = (int*)  (ws + (34u << 20) + 5 * 65536);

    k_rmsnorm<<<1024, 256, 0, stream>>>(x, nsc, t32, t16);
    k_gate   <<<1024, 256, 0, stream>>>(t32, gw, gb, idx, ew);
    k_bucket <<<   1, 256, 0, stream>>>(idx, ew, eoff, stok, sew, tslot);
    k_gemm<0><<<dim3(32, 64), 256, 0, stream>>>(w1, b1, t16, eoff, stok, sew, act, nullptr);
    k_gemm<1><<<dim3(16, 64), 256, 0, stream>>>(w2, b2, act, eoff, stok, sew, nullptr, obuf);
    k_combine<<<1024, 256, 0, stream>>>(x, obuf, tslot, out);
}

// Round 11
// 824.568 us; speedup vs baseline: 1.3573x; 1.1028x over previous
//
#include <hip/hip_runtime.h>
#include <hip/hip_bf16.h>

typedef __bf16 bf16x8 __attribute__((ext_vector_type(8)));
typedef __bf16 bf16x4 __attribute__((ext_vector_type(4)));
typedef float  f32x4v __attribute__((ext_vector_type(4)));

// ---------------- K1: RMSNorm -> t_f32, t_bf16 ----------------
__global__ __launch_bounds__(256) void k_rmsnorm(const float* __restrict__ x,
        const float* __restrict__ sc, float* __restrict__ t32,
        __bf16* __restrict__ t16)
{
    const int t = blockIdx.x, tid = threadIdx.x;
    const float4 v = ((const float4*)(x + (size_t)t * 1024))[tid];
    float ss = v.x*v.x + v.y*v.y + v.z*v.z + v.w*v.w;
    #pragma unroll
    for (int s = 32; s; s >>= 1) ss += __shfl_xor(ss, s, 64);
    __shared__ float red[4];
    if ((tid & 63) == 0) red[tid >> 6] = ss;
    __syncthreads();
    const float tot = red[0] + red[1] + red[2] + red[3];
    const float rs = rsqrtf(tot * (1.0f / 1024.0f) + 1e-5f);
    const float4 s4 = ((const float4*)sc)[tid];
    float4 o;
    o.x = v.x * rs * s4.x; o.y = v.y * rs * s4.y;
    o.z = v.z * rs * s4.z; o.w = v.w * rs * s4.w;
    ((float4*)(t32 + (size_t)t * 1024))[tid] = o;
    bf16x4 p;
    p[0] = (__bf16)o.x; p[1] = (__bf16)o.y; p[2] = (__bf16)o.z; p[3] = (__bf16)o.w;
    ((bf16x4*)(t16 + (size_t)t * 1024))[tid] = p;
}

// ---------------- K2: gate logits (fp32) + top4 + softmax ----------------
__global__ __launch_bounds__(256) void k_gate(const float* __restrict__ t32,
        const float* __restrict__ gw, const float* __restrict__ gb,
        int* __restrict__ idx, float* __restrict__ ew)
{
    const int t = blockIdx.x, tid = threadIdx.x;
    __shared__ float4 tl[256];
    __shared__ float part[4][64];
    tl[tid] = ((const float4*)(t32 + (size_t)t * 1024))[tid];
    __syncthreads();
    const int q = tid >> 6, e = tid & 63;
    const float4* w4 = (const float4*)(gw + (size_t)e * 1024 + q * 256);
    const float4* a4 = &tl[q * 64];
    float acc = 0.0f;
    #pragma unroll 8
    for (int i = 0; i < 64; ++i) {
        const float4 a = a4[i], b = w4[i];
        acc += a.x*b.x + a.y*b.y + a.z*b.z + a.w*b.w;
    }
    part[q][e] = acc;
    __syncthreads();
    if (tid < 64) {
        float cur = part[0][tid] + part[1][tid] + part[2][tid] + part[3][tid] + gb[tid];
        float vals[4]; int ids[4];
        #pragma unroll
        for (int k = 0; k < 4; ++k) {
            float m = cur;
            #pragma unroll
            for (int s = 32; s; s >>= 1) m = fmaxf(m, __shfl_xor(m, s, 64));
            const unsigned long long b = __ballot(cur == m);
            const int bi = __ffsll(b) - 1;
            vals[k] = m; ids[k] = bi;
            if (tid == bi) cur = -3.0e38f;
        }
        float ex[4], s = 0.0f;
        #pragma unroll
        for (int k = 0; k < 4; ++k) { ex[k] = expf(vals[k] - vals[0]); s += ex[k]; }
        if (tid < 4) { idx[t * 4 + tid] = ids[tid]; ew[t * 4 + tid] = ex[tid] / s; }
    }
}

// ---------------- K3: bucket (token,expert) pairs by expert ----------------
__global__ __launch_bounds__(256) void k_bucket(const int* __restrict__ idx,
        const float* __restrict__ ewv, int* __restrict__ eoff,
        int* __restrict__ slot_token, float* __restrict__ slot_ew,
        int* __restrict__ token_slots)
{
    __shared__ int cnt[64], cur[64];
    const int tid = threadIdx.x;
    if (tid < 64) cnt[tid] = 0;
    __syncthreads();
    for (int p = tid; p < 4096; p += 256) atomicAdd(&cnt[idx[p]], 1);
    __syncthreads();
    if (tid == 0) {
        int s = 0;
        for (int e = 0; e < 64; ++e) { eoff[e] = s; cur[e] = s; s += cnt[e]; }
        eoff[64] = s;
    }
    __syncthreads();
    for (int p = tid; p < 4096; p += 256) {
        const int e = idx[p];
        const int s = atomicAdd(&cur[e], 1);
        slot_token[s] = p >> 2;
        slot_ew[s] = ewv[p];
        token_slots[p] = s;
    }
}

// ---------------- K4/K5: producer/consumer grouped GEMM ----------------
// 512 thr = 8 waves: waves 0-5 consume (BM=96, A in regs, MFMA from LDS ring),
// waves 6-7 produce (stream 64-row W panel fp32->bf16 into 6-slot ring, 2 slots
// ahead, 16 loads in flight). LDS-flag sync, NO barriers in the K-loop.
template<int MODE>
__global__ __launch_bounds__(512, 2) void k_gemm(
        const float* __restrict__ W, const float* __restrict__ Bias,
        const __bf16* __restrict__ A,
        const int* __restrict__ eoff, const int* __restrict__ slot_token,
        const float* __restrict__ slot_ew,
        __bf16* __restrict__ act_out, __bf16* __restrict__ o_buf)
{
    constexpr int NPE = (MODE == 0) ? 2048 : 1024;
    const int e  = blockIdx.y;
    const int nt = blockIdx.x;                 // 64-col W panel
    const int off = eoff[e];
    const int count = eoff[e + 1] - off;
    if (count == 0) return;
    const int tid = threadIdx.x;
    const int wv = tid >> 6, l = tid & 63;
    const int lrow = l & 15, lq = l >> 4;

    __shared__ __attribute__((aligned(16))) unsigned char ring[6][8192];
    __shared__ int flags[8];                   // [0,1]=producer fill, [2..7]=consumer done
    volatile int* vf = flags;

    const float4* Wb4 = (const float4*)(W + ((size_t)e * NPE + (size_t)nt * 64) * 1024);

    const int nmt = (count + 95) / 96;
    for (int mt = 0; mt < nmt; ++mt) {
        __syncthreads();
        if (tid < 8) flags[tid] = 0;
        __syncthreads();

        if (wv < 6) {
            // ---------------- consumer: 16 A-rows in regs, MFMA from ring ----------------
            int slot = off + mt * 96 + wv * 16 + lrow;
            const int smax = off + count - 1;
            if (slot > smax) slot = smax;              // clamp pad rows (discarded)
            const int arow = (MODE == 0) ? slot_token[slot] : slot;
            const char* ap = (const char*)(A + (size_t)arow * 1024) + lq * 16;
            bf16x8 af[32];
            #pragma unroll
            for (int j = 0; j < 32; ++j)
                af[j] = *(const bf16x8*)(ap + j * 64);

            f32x4v acc[4];
            #pragma unroll
            for (int n = 0; n < 4; ++n) acc[n] = f32x4v{0.f, 0.f, 0.f, 0.f};

            #pragma unroll
            for (int kt = 0; kt < 16; ++kt) {
                while (vf[0] < kt + 1 || vf[1] < kt + 1) __builtin_amdgcn_s_sleep(1);
                __builtin_amdgcn_sched_barrier(0);
                const unsigned char* sb = &ring[kt % 6][0];
                #pragma unroll
                for (int kk = 0; kk < 2; ++kk) {
                    bf16x8 bf[4];
                    #pragma unroll
                    for (int n = 0; n < 4; ++n) {
                        const int r = n * 16 + lrow;
                        bf[n] = *(const bf16x8*)(sb + r * 128 +
                                 ((kk * 64 + lq * 16) ^ ((r & 7) << 4)));
                    }
                    #pragma unroll
                    for (int n = 0; n < 4; ++n)
                        acc[n] = __builtin_amdgcn_mfma_f32_16x16x32_bf16(
                                     af[kt * 2 + kk], bf[n], acc[n], 0, 0, 0);
                }
                asm volatile("s_waitcnt lgkmcnt(0)" ::: "memory");
                __builtin_amdgcn_sched_barrier(0);
                if (l == 0) flags[2 + wv] = kt + 1;    // release slot kt
            }

            // ---- epilogue ----
            #pragma unroll
            for (int n = 0; n < 4; ++n) {
                #pragma unroll
                for (int j = 0; j < 4; ++j) {
                    const int gm = mt * 96 + wv * 16 + lq * 4 + j;
                    const int gn = nt * 64 + n * 16 + lrow;
                    if (MODE == 0) {
                        float v = acc[n][j] + Bias[(size_t)e * NPE + gn];
                        const float partner = __shfl_xor(v, 1, 64);
                        if (!(l & 1) && gm < count) {
                            const float g  = fminf(v, 7.0f);
                            const float lv = fminf(fmaxf(partner, -7.0f), 7.0f);
                            const float r  = g / (1.0f + expf(-1.702f * g)) * (lv + 1.0f);
                            act_out[(size_t)(off + gm) * 1024 + (gn >> 1)] = (__bf16)r;
                        }
                    } else {
                        if (gm < count) {
                            const int sl = off + gm;
                            const float v = acc[n][j] + Bias[(size_t)e * NPE + gn];
                            o_buf[(size_t)sl * 1024 + gn] = (__bf16)(v * slot_ew[sl]);
                        }
                    }
                }
            }
        } else {
            // ---------------- producer p: stream 32 W rows/slot-half, 2 slots ahead ----------------
            const int p  = wv - 6;
            const int rg = p * 4 + lq;                 // row-group 0..7 (8 rows apart)
            const int swz = (rg & 7) << 4;
            const float4* base = Wb4 + (size_t)rg * 256 + lrow;
            float4 buf[3][8];

#define PLOAD(b, kt) do {                                                      \
    _Pragma("unroll")                                                          \
    for (int it_ = 0; it_ < 8; ++it_)                                          \
        buf[b][it_] = base[(size_t)it_ * 2048 + (kt) * 16];                    \
    } while (0)
#define PSTORE(b, kt) do {                                                     \
    unsigned char* sb_ = &ring[(kt) % 6][0] + rg * 128 + ((lrow * 8) ^ swz);   \
    _Pragma("unroll")                                                          \
    for (int it_ = 0; it_ < 8; ++it_) {                                        \
        bf16x4 q_;                                                             \
        q_[0] = (__bf16)buf[b][it_].x; q_[1] = (__bf16)buf[b][it_].y;          \
        q_[2] = (__bf16)buf[b][it_].z; q_[3] = (__bf16)buf[b][it_].w;          \
        *(bf16x4*)(sb_ + it_ * 1024) = q_;                                     \
    } } while (0)

            PLOAD(0, 0);
            PLOAD(1, 1);
            #pragma unroll
            for (int kt = 0; kt < 16; ++kt) {
                if (kt >= 6) {                          // ring: slot kt reuses kt-6
                    const int tgt = kt - 5;
                    while (vf[2] < tgt || vf[3] < tgt || vf[4] < tgt ||
                           vf[5] < tgt || vf[6] < tgt || vf[7] < tgt)
                        __builtin_amdgcn_s_sleep(1);
                }
                __builtin_amdgcn_sched_barrier(0);
                if (kt + 2 < 16) PLOAD((kt + 2) % 3, kt + 2);
                __builtin_amdgcn_sched_barrier(0);
                if (kt < 14)       asm volatile("s_waitcnt vmcnt(16)" ::: "memory");
                else if (kt == 14) asm volatile("s_waitcnt vmcnt(8)"  ::: "memory");
                else               asm volatile("s_waitcnt vmcnt(0)"  ::: "memory");
                __builtin_amdgcn_sched_barrier(0);
                PSTORE(kt % 3, kt);
                asm volatile("s_waitcnt lgkmcnt(0)" ::: "memory");
                __builtin_amdgcn_sched_barrier(0);
                if (l == 0) flags[p] = kt + 1;          // publish slot kt (half p)
            }
#undef PLOAD
#undef PSTORE
        }
    }
}

// ---------------- K6: out = x + sum_k o_buf[slot(t,k)] (obuf bf16) ----------------
__global__ __launch_bounds__(256) void k_combine(const float* __restrict__ x,
        const __bf16* __restrict__ o_buf, const int* __restrict__ tslot,
        float* __restrict__ out)
{
    const int t = blockIdx.x, tid = threadIdx.x;
    float4 r = ((const float4*)(x + (size_t)t * 1024))[tid];
    #pragma unroll
    for (int k = 0; k < 4; ++k) {
        const int s = tslot[t * 4 + k];
        const bf16x4 o = ((const bf16x4*)(o_buf + (size_t)s * 1024))[tid];
        r.x += (float)o[0]; r.y += (float)o[1];
        r.z += (float)o[2]; r.w += (float)o[3];
    }
    ((float4*)(out + (size_t)t * 1024))[tid] = r;
}

extern "C" void kernel_launch(void* const* d_in, const int* in_sizes, int n_in,
                              void* d_out, int out_size, void* d_ws, size_t ws_size,
                              hipStream_t stream)
{
    const float* x   = (const float*)d_in[0];
    const float* nsc = (const float*)d_in[1];
    const float* gw  = (const float*)d_in[2];
    const float* gb  = (const float*)d_in[3];
    const float* w1  = (const float*)d_in[4];
    const float* b1  = (const float*)d_in[5];
    const float* w2  = (const float*)d_in[6];
    const float* b2  = (const float*)d_in[7];
    float* out = (float*)d_out;
    (void)in_sizes; (void)n_in; (void)out_size; (void)ws_size;

    char* ws = (char*)d_ws;
    float*  t32   = (float*)(ws);                                  // 4 MiB
    __bf16* t16   = (__bf16*)(ws + (4u  << 20));                   // 2 MiB
    __bf16* act   = (__bf16*)(ws + (6u  << 20));                   // 8.4 MiB
    __bf16* obuf  = (__bf16*)(ws + (16u << 20));                   // 8.4 MiB
    int*    idx   = (int*)  (ws + (34u << 20));
    float*  ew    = (float*)(ws + (34u << 20) + 1 * 65536);
    int*    stok  = (int*)  (ws + (34u << 20) + 2 * 65536);
    float*  sew   = (float*)(ws + (34u << 20) + 3 * 65536);
    int*    tslot = (int*)  (ws + (34u << 20) + 4 * 65536);
    int*    eoff  = (int*)  (ws + (34u << 20) + 5 * 65536);

    k_rmsnorm<<<1024, 256, 0, stream>>>(x, nsc, t32, t16);
    k_gate   <<<1024, 256, 0, stream>>>(t32, gw, gb, idx, ew);
    k_bucket <<<   1, 256, 0, stream>>>(idx, ew, eoff, stok, sew, tslot);
    k_gemm<0><<<dim3(32, 64), 512, 0, stream>>>(w1, b1, t16, eoff, stok, sew, act, nullptr);
    k_gemm<1><<<dim3(16, 64), 512, 0, stream>>>(w2, b2, act, eoff, stok, sew, nullptr, obuf);
    k_combine<<<1024, 256, 0, stream>>>(x, obuf, tslot, out);
}

// Round 12
// 302.148 us; speedup vs baseline: 3.7041x; 2.7290x over previous
//
#include <hip/hip_runtime.h>
#include <hip/hip_bf16.h>

#define GLOBAL_AS __attribute__((address_space(1)))
#define LDS_AS    __attribute__((address_space(3)))

typedef __bf16 bf16x8 __attribute__((ext_vector_type(8)));
typedef __bf16 bf16x4 __attribute__((ext_vector_type(4)));
typedef float  f32x4v __attribute__((ext_vector_type(4)));

// ---------------- K1: RMSNorm -> t_f32, t_bf16 ----------------
__global__ __launch_bounds__(256) void k_rmsnorm(const float* __restrict__ x,
        const float* __restrict__ sc, float* __restrict__ t32,
        __bf16* __restrict__ t16)
{
    const int t = blockIdx.x, tid = threadIdx.x;
    const float4 v = ((const float4*)(x + (size_t)t * 1024))[tid];
    float ss = v.x*v.x + v.y*v.y + v.z*v.z + v.w*v.w;
    #pragma unroll
    for (int s = 32; s; s >>= 1) ss += __shfl_xor(ss, s, 64);
    __shared__ float red[4];
    if ((tid & 63) == 0) red[tid >> 6] = ss;
    __syncthreads();
    const float tot = red[0] + red[1] + red[2] + red[3];
    const float rs = rsqrtf(tot * (1.0f / 1024.0f) + 1e-5f);
    const float4 s4 = ((const float4*)sc)[tid];
    float4 o;
    o.x = v.x * rs * s4.x; o.y = v.y * rs * s4.y;
    o.z = v.z * rs * s4.z; o.w = v.w * rs * s4.w;
    ((float4*)(t32 + (size_t)t * 1024))[tid] = o;
    bf16x4 p;
    p[0] = (__bf16)o.x; p[1] = (__bf16)o.y; p[2] = (__bf16)o.z; p[3] = (__bf16)o.w;
    ((bf16x4*)(t16 + (size_t)t * 1024))[tid] = p;
}

// ---------------- K2: gate logits (fp32) + top4 + softmax ----------------
__global__ __launch_bounds__(256) void k_gate(const float* __restrict__ t32,
        const float* __restrict__ gw, const float* __restrict__ gb,
        int* __restrict__ idx, float* __restrict__ ew)
{
    const int t = blockIdx.x, tid = threadIdx.x;
    __shared__ float4 tl[256];
    __shared__ float part[4][64];
    tl[tid] = ((const float4*)(t32 + (size_t)t * 1024))[tid];
    __syncthreads();
    const int q = tid >> 6, e = tid & 63;
    const float4* w4 = (const float4*)(gw + (size_t)e * 1024 + q * 256);
    const float4* a4 = &tl[q * 64];
    float acc = 0.0f;
    #pragma unroll 8
    for (int i = 0; i < 64; ++i) {
        const float4 a = a4[i], b = w4[i];
        acc += a.x*b.x + a.y*b.y + a.z*b.z + a.w*b.w;
    }
    part[q][e] = acc;
    __syncthreads();
    if (tid < 64) {
        float cur = part[0][tid] + part[1][tid] + part[2][tid] + part[3][tid] + gb[tid];
        float vals[4]; int ids[4];
        #pragma unroll
        for (int k = 0; k < 4; ++k) {
            float m = cur;
            #pragma unroll
            for (int s = 32; s; s >>= 1) m = fmaxf(m, __shfl_xor(m, s, 64));
            const unsigned long long b = __ballot(cur == m);
            const int bi = __ffsll(b) - 1;
            vals[k] = m; ids[k] = bi;
            if (tid == bi) cur = -3.0e38f;
        }
        float ex[4], s = 0.0f;
        #pragma unroll
        for (int k = 0; k < 4; ++k) { ex[k] = expf(vals[k] - vals[0]); s += ex[k]; }
        if (tid < 4) { idx[t * 4 + tid] = ids[tid]; ew[t * 4 + tid] = ex[tid] / s; }
    }
}

// ---------------- K3: bucket (token,expert) pairs by expert ----------------
__global__ __launch_bounds__(256) void k_bucket(const int* __restrict__ idx,
        const float* __restrict__ ewv, int* __restrict__ eoff,
        int* __restrict__ slot_token, float* __restrict__ slot_ew,
        int* __restrict__ token_slots)
{
    __shared__ int cnt[64], cur[64];
    const int tid = threadIdx.x;
    if (tid < 64) cnt[tid] = 0;
    __syncthreads();
    for (int p = tid; p < 4096; p += 256) atomicAdd(&cnt[idx[p]], 1);
    __syncthreads();
    if (tid == 0) {
        int s = 0;
        for (int e = 0; e < 64; ++e) { eoff[e] = s; cur[e] = s; s += cnt[e]; }
        eoff[64] = s;
    }
    __syncthreads();
    for (int p = tid; p < 4096; p += 256) {
        const int e = idx[p];
        const int s = atomicAdd(&cur[e], 1);
        slot_token[s] = p >> 2;
        slot_ew[s] = ewv[p];
        token_slots[p] = s;
    }
}

// ---------------- K4/K5: grouped GEMM, BM=96, BN=256/128, BK=64 ----------------
// Delivered-byte-minimized: BN doubled (A re-reads halved), BM=96 (A rows -25%).
// A double-buffered via global_load_lds (pre-swizzled source); B single LDS
// buffer + 1-step register lookahead. 2 blocks/CU, 256-VGPR tier (256,2).
template<int MODE>
__global__ __launch_bounds__(256, 2) void k_gemm(
        const float* __restrict__ W, const float* __restrict__ Bias,
        const __bf16* __restrict__ A,
        const int* __restrict__ eoff, const int* __restrict__ slot_token,
        const float* __restrict__ slot_ew,
        __bf16* __restrict__ act_out, __bf16* __restrict__ o_buf)
{
    constexpr int NPE = (MODE == 0) ? 2048 : 1024;
    constexpr int BN  = (MODE == 0) ?  256 :  128;   // N-tile (W rows/panel)
    constexpr int NIT = BN / 16;                      // float4 loads per thread
    constexpr int NF  = BN / 32;                      // N-frags per wave
    const int d  = blockIdx.y * gridDim.x + blockIdx.x;      // 512 blocks
    const int e  = (d & 7) * 8 + ((d >> 3) & 7);              // same-e -> same XCD
    const int nt = d >> 6;
    const int off = eoff[e];
    const int count = eoff[e + 1] - off;
    if (count == 0) return;
    const int tid = threadIdx.x;
    const int wv = tid >> 6, l = tid & 63;
    const int wm = wv >> 1, wn = wv & 1;              // 2M(48) x 2N(BN/2)
    const int lrow = l & 15, lq = l >> 4;

    __shared__ __attribute__((aligned(16))) unsigned char lds_a[2][12288];
    __shared__ __attribute__((aligned(16))) unsigned char lds_b[BN * 128];

    const float* Wb = W + ((size_t)e * NPE + (size_t)nt * BN) * 1024;

#define DMA_A(sbuf, kt) do {                                                   \
    _Pragma("unroll")                                                          \
    for (int i_ = 0; i_ < 3; ++i_)                                             \
        __builtin_amdgcn_global_load_lds(                                      \
            (const GLOBAL_AS void*)(asrc[i_] + (kt) * 128),                    \
            (LDS_AS void*)&lds_a[sbuf][(wv * 3 + i_) * 1024], 16, 0, 0);       \
    } while (0)

#define LOAD_B(kt) do {                                                        \
    _Pragma("unroll")                                                          \
    for (int it_ = 0; it_ < NIT; ++it_) {                                      \
        const int fid_ = it_ * 256 + tid;                                      \
        bv[it_] = *(const float4*)(Wb + (size_t)(fid_ >> 4) * 1024             \
                                   + (kt) * 64 + (fid_ & 15) * 4);             \
    } } while (0)

#define WRITE_B() do {                                                         \
    _Pragma("unroll")                                                          \
    for (int it_ = 0; it_ < NIT; ++it_) {                                      \
        const int fid_ = it_ * 256 + tid;                                      \
        const int row_ = fid_ >> 4, c4_ = fid_ & 15;                           \
        bf16x4 p_;                                                             \
        p_[0] = (__bf16)bv[it_].x; p_[1] = (__bf16)bv[it_].y;                  \
        p_[2] = (__bf16)bv[it_].z; p_[3] = (__bf16)bv[it_].w;                  \
        *(bf16x4*)(&lds_b[row_ * 128 +                                         \
                   ((c4_ * 8) ^ ((row_ & 7) << 4))]) = p_;                     \
    } } while (0)

#define COMPUTE(cbuf) do {                                                     \
    _Pragma("unroll")                                                          \
    for (int kk_ = 0; kk_ < 2; ++kk_) {                                        \
        bf16x8 af_[3], bf_[NF];                                                \
        _Pragma("unroll")                                                      \
        for (int m_ = 0; m_ < 3; ++m_) {                                       \
            const int row_ = wm * 48 + m_ * 16 + lrow;                         \
            af_[m_] = *(const bf16x8*)(&lds_a[cbuf][row_ * 128 +               \
                      ((kk_ * 64 + lq * 16) ^ ((row_ & 7) << 4))]);            \
        }                                                                      \
        _Pragma("unroll")                                                      \
        for (int n_ = 0; n_ < NF; ++n_) {                                      \
            const int row_ = wn * (BN / 2) + n_ * 16 + lrow;                   \
            bf_[n_] = *(const bf16x8*)(&lds_b[row_ * 128 +                     \
                      ((kk_ * 64 + lq * 16) ^ ((row_ & 7) << 4))]);            \
        }                                                                      \
        _Pragma("unroll")                                                      \
        for (int m_ = 0; m_ < 3; ++m_)                                         \
            _Pragma("unroll")                                                  \
            for (int n_ = 0; n_ < NF; ++n_)                                    \
                acc[m_][n_] = __builtin_amdgcn_mfma_f32_16x16x32_bf16(         \
                                  af_[m_], bf_[n_], acc[m_][n_], 0, 0, 0);     \
    } } while (0)

#define VMC0()  asm volatile("s_waitcnt vmcnt(0)" ::: "memory")
#define LGKM0() asm volatile("s_waitcnt lgkmcnt(0)" ::: "memory")
#define SB()    __builtin_amdgcn_sched_barrier(0)
#define BAR()   __builtin_amdgcn_s_barrier()

    const int nmt = (count + 95) / 96;
    for (int mt = 0; mt < nmt; ++mt) {
        // per-lane A source pointers (pre-swizzled global; linear LDS dest)
        const unsigned char* asrc[3];
        #pragma unroll
        for (int i = 0; i < 3; ++i) {
            const int chunk = wv * 3 + i;                 // 0..11
            const int row = chunk * 8 + (l >> 3);         // 0..95
            const int colbyte = ((l & 7) ^ (l >> 3)) << 4;
            int arow;
            if (MODE == 0) {
                int slot = off + mt * 96 + row;
                const int smax = off + count - 1;
                if (slot > smax) slot = smax;             // clamp pads (discarded)
                arow = slot_token[slot];
            } else {
                arow = off + mt * 96 + row;               // act has row slack
            }
            asrc[i] = (const unsigned char*)A + (size_t)arow * 2048 + colbyte;
        }

        f32x4v acc[3][NF];
        #pragma unroll
        for (int m = 0; m < 3; ++m)
            #pragma unroll
            for (int n = 0; n < NF; ++n)
                acc[m][n] = f32x4v{0.f, 0.f, 0.f, 0.f};

        float4 bv[NIT];

        // ---- prologue: A(0),B(0) -> LDS; A(1),B(1) in flight ----
        DMA_A(0, 0); SB();
        LOAD_B(0);
        WRITE_B();                       // reg-dep drains B(0) (and older A-dma)
        VMC0(); LGKM0(); SB(); BAR(); SB();
        DMA_A(1, 1); SB();
        LOAD_B(1); SB();

        #pragma unroll 1
        for (int kt = 0; kt < 16; ++kt) {
            COMPUTE(kt & 1);
            if (kt == 15) break;
            BAR(); SB();                 // all waves done reading lds_b/lds_a[kt&1]
            WRITE_B();                   // B(kt+1); implicit in-order vmcnt drain
                                         // also retires A(kt+1)'s dma ops
            if (kt < 14) {
                DMA_A(kt & 1, kt + 2); SB();
                LOAD_B(kt + 2);
            }
            LGKM0(); SB(); BAR(); SB();
        }

        // ---- epilogue ----
        #pragma unroll
        for (int m = 0; m < 3; ++m) {
            #pragma unroll
            for (int n = 0; n < NF; ++n) {
                #pragma unroll
                for (int j = 0; j < 4; ++j) {
                    const int row = wm * 48 + m * 16 + lq * 4 + j;
                    const int gn = nt * BN + wn * (BN / 2) + n * 16 + lrow;
                    const int gm = mt * 96 + row;
                    if (MODE == 0) {
                        float v = acc[m][n][j] + Bias[(size_t)e * NPE + gn];
                        const float partner = __shfl_xor(v, 1, 64);
                        if (!(l & 1) && gm < count) {
                            const float g  = fminf(v, 7.0f);
                            const float lv = fminf(fmaxf(partner, -7.0f), 7.0f);
                            const float r  = g / (1.0f + expf(-1.702f * g)) * (lv + 1.0f);
                            act_out[(size_t)(off + gm) * 1024 + (gn >> 1)] = (__bf16)r;
                        }
                    } else {
                        if (gm < count) {
                            const int sl = off + gm;
                            const float v = acc[m][n][j] + Bias[(size_t)e * NPE + gn];
                            o_buf[(size_t)sl * 1024 + gn] = (__bf16)(v * slot_ew[sl]);
                        }
                    }
                }
            }
        }
        BAR();                           // protect LDS reuse across mt
    }
#undef DMA_A
#undef LOAD_B
#undef WRITE_B
#undef COMPUTE
#undef VMC0
#undef LGKM0
#undef SB
#undef BAR
}

// ---------------- K6: out = x + sum_k o_buf[slot(t,k)] (obuf bf16) ----------------
__global__ __launch_bounds__(256) void k_combine(const float* __restrict__ x,
        const __bf16* __restrict__ o_buf, const int* __restrict__ tslot,
        float* __restrict__ out)
{
    const int t = blockIdx.x, tid = threadIdx.x;
    float4 r = ((const float4*)(x + (size_t)t * 1024))[tid];
    #pragma unroll
    for (int k = 0; k < 4; ++k) {
        const int s = tslot[t * 4 + k];
        const bf16x4 o = ((const bf16x4*)(o_buf + (size_t)s * 1024))[tid];
        r.x += (float)o[0]; r.y += (float)o[1];
        r.z += (float)o[2]; r.w += (float)o[3];
    }
    ((float4*)(out + (size_t)t * 1024))[tid] = r;
}

extern "C" void kernel_launch(void* const* d_in, const int* in_sizes, int n_in,
                              void* d_out, int out_size, void* d_ws, size_t ws_size,
                              hipStream_t stream)
{
    const float* x   = (const float*)d_in[0];
    const float* nsc = (const float*)d_in[1];
    const float* gw  = (const float*)d_in[2];
    const float* gb  = (const float*)d_in[3];
    const float* w1  = (const float*)d_in[4];
    const float* b1  = (const float*)d_in[5];
    const float* w2  = (const float*)d_in[6];
    const float* b2  = (const float*)d_in[7];
    float* out = (float*)d_out;
    (void)in_sizes; (void)n_in; (void)out_size; (void)ws_size;

    char* ws = (char*)d_ws;
    float*  t32   = (float*)(ws);                                  // 4 MiB
    __bf16* t16   = (__bf16*)(ws + (4u  << 20));                   // 2 MiB
    __bf16* act   = (__bf16*)(ws + (6u  << 20));                   // 10 MiB slack
    __bf16* obuf  = (__bf16*)(ws + (16u << 20));                   // 8.4 MiB
    int*    idx   = (int*)  (ws + (34u << 20));
    float*  ew    = (float*)(ws + (34u << 20) + 1 * 65536);
    int*    stok  = (int*)  (ws + (34u << 20) + 2 * 65536);
    float*  sew   = (float*)(ws + (34u << 20) + 3 * 65536);
    int*    tslot = (int*)  (ws + (34u << 20) + 4 * 65536);
    int*    eoff  = (int*)  (ws + (34u << 20) + 5 * 65536);

    k_rmsnorm<<<1024, 256, 0, stream>>>(x, nsc, t32, t16);
    k_gate   <<<1024, 256, 0, stream>>>(t32, gw, gb, idx, ew);
    k_bucket <<<   1, 256, 0, stream>>>(idx, ew, eoff, stok, sew, tslot);
    k_gemm<0><<<dim3(8, 64), 256, 0, stream>>>(w1, b1, t16, eoff, stok, sew, act, nullptr);
    k_gemm<1><<<dim3(8, 64), 256, 0, stream>>>(w2, b2, act, eoff, stok, sew, nullptr, obuf);
    k_combine<<<1024, 256, 0, stream>>>(x, obuf, tslot, out);
}